// Round 8
// baseline (559.256 us; speedup 1.0000x reference)
//
#include <hip/hip_runtime.h>
#include <hip/hip_cooperative_groups.h>
#include <math.h>

namespace cg = cooperative_groups;

#define LR 0.001f

// Sizes
#define B   64
#define IN  2048
#define HID 512
#define OUT 128
#define GB  16          // batch-group size
#define NG  (B/GB)      // 4 groups
#define NBLK 256
#define NTHR 512

typedef float vf2 __attribute__((ext_vector_type(2)));
typedef float vf4 __attribute__((ext_vector_type(4)));

// ws layout (floats), shared by coop + fallback paths
#define WS_ZP  0                         // coop: [GB][128][HID] = 1,048,576
#define WS_GBW (WS_ZP + GB*128*HID)      // [B][HID] = 32768
// fallback layout (disjoint use of same region is fine; paths never mix)
#define FQC    16
#define FWS_ZP    0                      // [B][FQC][HID] = 524288
#define FWS_TANH  (FWS_ZP + B*FQC*HID)
#define FWS_ZOP   (FWS_TANH + B*HID)
#define FWS_GB    (FWS_ZOP + B*8*OUT)

// out layout (floats)
#define O_L2N   0
#define O_DW0   (B*OUT)
#define O_DB0   (O_DW0 + B*IN*HID)
#define O_DW1   (O_DB0 + B*HID)
#define O_DB1   (O_DW1 + B*HID*OUT)

// ===================== cooperative mega-kernel path =====================

// fwd1 work unit: one (b,qc) pair = 64 q-rows; 512 threads:
// sub = tid>>7 owns 16 q-rows, thread owns float4 at h=(tid&127)*4.
// Plain loads: we WANT the dW0 slab L3-resident for this group's upd0.
__device__ __forceinline__ void fwd1_pair(const float* __restrict__ x,
                                          const float* __restrict__ W0,
                                          const float* __restrict__ dW0,
                                          float* __restrict__ zp,
                                          int bb, int p, int tid) {
    const int bl = p >> 5;            // 0..15
    const int b  = bb + bl;
    const int qc = p & 31;            // 0..31
    const int sub = tid >> 7;         // 0..3
    const int h = (tid & 127) << 2;   // 0..508
    const int q0 = qc * 64 + sub * 16;
    const float* xr = x + b * IN;
    float4 acc = make_float4(0.f, 0.f, 0.f, 0.f);
    #pragma unroll 4
    for (int qi = 0; qi < 16; ++qi) {
        const int q = q0 + qi;
        const float xv = xr[q];
        const float4 w0 = *(const float4*)(W0 + q * HID + h);
        const float4 dw = *(const float4*)(dW0 + ((size_t)(b * IN + q)) * HID + h);
        acc.x += xv * (w0.x + dw.x);
        acc.y += xv * (w0.y + dw.y);
        acc.z += xv * (w0.z + dw.z);
        acc.w += xv * (w0.w + dw.w);
    }
    *(float4*)(zp + ((size_t)(bl * 128 + qc * 4 + sub)) * HID + h) = acc;
}

// upd0: new_dW0 = dW0 - LR*x*gb over one group slab. dW0 read should be
// L3-hit (slab read by fwd1 ~80MB of traffic ago). NT stores for output.
__device__ __forceinline__ void upd0_work(const float* __restrict__ dW0,
                                          const float* __restrict__ x,
                                          const float* __restrict__ gbw,
                                          float* __restrict__ out_dW0,
                                          int bb, int worker, int nworkers) {
    const int n4 = GB * IN * HID / 4;          // 4,194,304
    const size_t base = (size_t)bb * IN * HID / 4;
    for (int i = worker; i < n4; i += nworkers) {
        const int h4 = i & (HID / 4 - 1);
        const int rest = i >> 7;
        const int q = rest & (IN - 1);
        const int b = bb + (rest >> 11);
        const size_t j = base + i;
        const float4 dw = ((const float4*)dW0)[j];
        const float xv = x[b * IN + q];
        const float4 g = *(const float4*)(gbw + b * HID + h4 * 4);
        vf4 o;
        o.x = dw.x - LR * xv * g.x;
        o.y = dw.y - LR * xv * g.y;
        o.z = dw.z - LR * xv * g.z;
        o.w = dw.w - LR * xv * g.w;
        __builtin_nontemporal_store(o, (vf4*)out_dW0 + j);
    }
}

// B phase: per-b fwd2 + stats + bwd1, one 512-thread block per b.
// tanh/zo/g2 live in LDS only.
__device__ __forceinline__ void bphase(const float* __restrict__ ut,
                                       const float* __restrict__ b0,
                                       const float* __restrict__ W1,
                                       const float* __restrict__ b1,
                                       const float* __restrict__ db0,
                                       const float* __restrict__ dW1,
                                       const float* __restrict__ db1,
                                       const float* __restrict__ zp,
                                       float* __restrict__ gbw,
                                       float* __restrict__ out,
                                       int bb, int bl, int tid) {
    __shared__ float sth[HID];
    __shared__ float szo[16][OUT];
    __shared__ float sred[2][3];
    __shared__ float sg2[OUT];
    const int b = bb + bl;

    // 1: z-sum over 128 chunks + bias + tanh
    {
        const int h = tid;
        float zs = 0.f;
        const float* p = zp + (size_t)(bl * 128) * HID + h;
        #pragma unroll 8
        for (int c = 0; c < 128; ++c) zs += p[(size_t)c * HID];
        sth[h] = tanhf(zs + b0[h] + db0[b * HID + h]);
    }
    __syncthreads();

    // 2: zo partials, float4 over o: thread (hc=tid>>5, oq=(tid&31)*4)
    // sums 32 h rows.
    {
        const int oq = (tid & 31) * 4;
        const int hc = tid >> 5;          // 0..15
        float4 acc = make_float4(0.f, 0.f, 0.f, 0.f);
        #pragma unroll 4
        for (int i = 0; i < 32; ++i) {
            const int hh = hc * 32 + i;
            const float th = sth[hh];
            const float4 w1 = *(const float4*)(W1 + hh * OUT + oq);
            const float4 dw = *(const float4*)(dW1 + ((size_t)b * HID + hh) * OUT + oq);
            acc.x += th * (w1.x + dw.x);
            acc.y += th * (w1.y + dw.y);
            acc.z += th * (w1.z + dw.z);
            acc.w += th * (w1.w + dw.w);
        }
        *(float4*)&szo[hc][oq] = acc;
    }
    __syncthreads();

    // 3: full zo + row stats (tid < 128, two waves)
    if (tid < 128) {
        const int o = tid;
        float zo = b1[o] + db1[b * OUT + o];
        #pragma unroll
        for (int k = 0; k < 16; ++k) zo += szo[k][o];
        const float tr = ut[b * OUT + o];
        float a = zo * zo, c2 = tr * tr, d = tr * zo;
        for (int off = 32; off; off >>= 1) {
            a  += __shfl_xor(a,  off, 64);
            c2 += __shfl_xor(c2, off, 64);
            d  += __shfl_xor(d,  off, 64);
        }
        const int wv = tid >> 6;
        if ((tid & 63) == 0) { sred[wv][0] = a; sred[wv][1] = c2; sred[wv][2] = d; }
        szo[0][o] = zo;   // stash zo (only thread o touches column o)
    }
    __syncthreads();
    const float l2  = sred[0][0] + sred[1][0];              // squared norm
    const float ntv = fmaxf(sqrtf(sred[0][1] + sred[1][1]), 1e-12f);
    const float tdot = (sred[0][2] + sred[1][2]) / ntv;
    const float s = 2.0f * tdot / (l2 * l2);
    if (tid < 128) {
        const int o = tid;
        const float zo = szo[0][o];
        const float tr = ut[b * OUT + o];
        const float g2 = -(tr / ntv) / l2 + s * zo;
        sg2[o] = g2;
        out[O_L2N + b * OUT + o] = zo / l2;
        out[O_DB1 + b * OUT + o] = db1[b * OUT + o] - LR * g2;
    }
    __syncthreads();

    // 4: bwd through layer 2: wave wv owns 64 h rows, lane owns 2 o
    {
        const int wv = tid >> 6, lane = tid & 63, o2 = lane * 2;
        const float g2x = sg2[o2], g2y = sg2[o2 + 1];
        float* out_dW1 = out + O_DW1;
        for (int i = 0; i < 64; ++i) {
            const int h = wv * 64 + i;
            const size_t idx = ((size_t)b * HID + h) * OUT + o2;
            const float2 dw = *(const float2*)(dW1 + idx);
            const float2 w1 = *(const float2*)(W1 + h * OUT + o2);
            float part = g2x * (w1.x + dw.x) + g2y * (w1.y + dw.y);
            for (int off = 32; off; off >>= 1) part += __shfl_xor(part, off, 64);
            const float th = sth[h];
            vf2 nd;
            nd.x = dw.x - LR * th * g2x;
            nd.y = dw.y - LR * th * g2y;
            __builtin_nontemporal_store(nd, (vf2*)(out_dW1 + idx));
            if (lane == 0) {
                const float gbv = (1.f - th * th) * part;
                gbw[b * HID + h] = gbv;
                out[O_DB0 + b * HID + h] = db0[b * HID + h] - LR * gbv;
            }
        }
    }
}

__global__ __launch_bounds__(NTHR, 2)
void k_mega(const float* x, const float* ut, const float* W0, const float* b0,
            const float* W1, const float* b1, const float* dW0, const float* db0,
            const float* dW1, const float* db1, float* out, float* zp, float* gbw) {
    cg::grid_group grid = cg::this_grid();
    const int bid = blockIdx.x, tid = threadIdx.x;

    // A0: fwd1 for group 0 (256 blocks x 2 pairs)
    fwd1_pair(x, W0, dW0, zp, 0, bid * 2, tid);
    fwd1_pair(x, W0, dW0, zp, 0, bid * 2 + 1, tid);

    for (int g = 0; g < NG; ++g) {
        const int bb = g * GB;
        grid.sync();
        // B_g: 16 blocks, one per b
        if (bid < GB) {
            bphase(ut, b0, W1, b1, db0, dW1, db1, zp, gbw, out, bb, bid, tid);
        }
        grid.sync();
        // C_g: upd0(g) || fwd1(g+1)
        if (g < NG - 1) {
            if (bid < 128) {
                upd0_work(dW0, x, gbw, out + O_DW0, bb, bid * NTHR + tid, 128 * NTHR);
            } else {
                const int p0 = (bid - 128) * 4;
                fwd1_pair(x, W0, dW0, zp, bb + GB, p0, tid);
                fwd1_pair(x, W0, dW0, zp, bb + GB, p0 + 1, tid);
                fwd1_pair(x, W0, dW0, zp, bb + GB, p0 + 2, tid);
                fwd1_pair(x, W0, dW0, zp, bb + GB, p0 + 3, tid);
            }
        } else {
            upd0_work(dW0, x, gbw, out + O_DW0, bb, bid * NTHR + tid, NBLK * NTHR);
        }
    }
}

// ===================== fallback path (round-3, proven 164 us) =====================

__global__ void k_fwd1f(const float* __restrict__ x, const float* __restrict__ W0,
                        const float* __restrict__ dW0, float* __restrict__ zp) {
    const int b = blockIdx.x;
    const int q0 = blockIdx.y * (IN / FQC);
    const int h = threadIdx.x * 4;
    const float* xr = x + b * IN;
    float4 acc = make_float4(0.f, 0.f, 0.f, 0.f);
    for (int qi = 0; qi < IN / FQC; ++qi) {
        const int q = q0 + qi;
        const float xv = xr[q];
        const float4 w0 = *(const float4*)(W0 + q * HID + h);
        const float4 dw = *(const float4*)(dW0 + ((size_t)(b * IN + q)) * HID + h);
        acc.x += xv * (w0.x + dw.x);
        acc.y += xv * (w0.y + dw.y);
        acc.z += xv * (w0.z + dw.z);
        acc.w += xv * (w0.w + dw.w);
    }
    *(float4*)(zp + (b * FQC + blockIdx.y) * HID + h) = acc;
}

__global__ void k_fwd2f(const float* __restrict__ zp, const float* __restrict__ b0,
                        const float* __restrict__ db0, const float* __restrict__ W1,
                        const float* __restrict__ dW1, float* __restrict__ tanhv,
                        float* __restrict__ zop) {
    const int b = blockIdx.x;
    const int h0 = blockIdx.y * 64;
    const int tid = threadIdx.x;
    __shared__ float sth[64];
    if (tid < 64) {
        const int h = h0 + tid;
        float zsum = 0.f;
        const float* p = zp + (b * FQC) * HID + h;
        #pragma unroll
        for (int qc = 0; qc < FQC; ++qc) zsum += p[qc * HID];
        const float th = tanhf(zsum + b0[h] + db0[b * HID + h]);
        tanhv[b * HID + h] = th;
        sth[tid] = th;
    }
    __syncthreads();
    const int o = tid;
    float acc = 0.f;
    #pragma unroll 8
    for (int hi = 0; hi < 64; ++hi) {
        const int h = h0 + hi;
        acc += sth[hi] * (W1[h * OUT + o] + dW1[(b * HID + h) * OUT + o]);
    }
    zop[(b * 8 + blockIdx.y) * OUT + o] = acc;
}

__global__ void k_bwd1f(const float* __restrict__ zop, const float* __restrict__ b1,
                        const float* __restrict__ db1, const float* __restrict__ ut,
                        const float* __restrict__ W1, const float* __restrict__ dW1,
                        const float* __restrict__ tanhv, const float* __restrict__ db0,
                        float* __restrict__ out_l2n, float* __restrict__ out_db1,
                        float* __restrict__ out_dW1, float* __restrict__ out_db0,
                        float* __restrict__ gb) {
    const int b = blockIdx.x;
    const int w = threadIdx.x >> 6;
    const int lane = threadIdx.x & 63;
    const int o2 = lane * 2;
    float2 zo;
    zo.x = b1[o2]     + db1[b * OUT + o2];
    zo.y = b1[o2 + 1] + db1[b * OUT + o2 + 1];
    #pragma unroll
    for (int c = 0; c < 8; ++c) {
        const float2 zp2 = *(const float2*)(zop + (b * 8 + c) * OUT + o2);
        zo.x += zp2.x; zo.y += zp2.y;
    }
    const float2 tr = *(const float2*)(ut + b * OUT + o2);
    float a = zo.x * zo.x + zo.y * zo.y;
    float c2 = tr.x * tr.x + tr.y * tr.y;
    float d  = tr.x * zo.x + tr.y * zo.y;
    for (int off = 32; off; off >>= 1) {
        a  += __shfl_xor(a,  off, 64);
        c2 += __shfl_xor(c2, off, 64);
        d  += __shfl_xor(d,  off, 64);
    }
    const float l2 = a;
    const float nt = fmaxf(sqrtf(c2), 1e-12f);
    const float tdot = d / nt;
    const float s = 2.0f * tdot / (l2 * l2);
    float2 g2;
    g2.x = -(tr.x / nt) / l2 + s * zo.x;
    g2.y = -(tr.y / nt) / l2 + s * zo.y;
    if (blockIdx.y == 0 && w == 0) {
        *(float2*)(out_l2n + b * OUT + o2) = make_float2(zo.x / l2, zo.y / l2);
        *(float2*)(out_db1 + b * OUT + o2) =
            make_float2(db1[b * OUT + o2] - LR * g2.x, db1[b * OUT + o2 + 1] - LR * g2.y);
    }
    for (int i = 0; i < 16; ++i) {
        const int h = blockIdx.y * 64 + w * 16 + i;
        const int idx = (b * HID + h) * OUT + o2;
        const float2 dw = *(const float2*)(dW1 + idx);
        const float2 w1 = *(const float2*)(W1 + h * OUT + o2);
        float part = g2.x * (w1.x + dw.x) + g2.y * (w1.y + dw.y);
        for (int off = 32; off; off >>= 1) part += __shfl_xor(part, off, 64);
        const float th = tanhv[b * HID + h];
        vf2 nd;
        nd.x = dw.x - LR * th * g2.x;
        nd.y = dw.y - LR * th * g2.y;
        __builtin_nontemporal_store(nd, (vf2*)(out_dW1 + idx));
        if (lane == 0) {
            const float gbv = (1.f - th * th) * part;
            gb[b * HID + h] = gbv;
            out_db0[b * HID + h] = db0[b * HID + h] - LR * gbv;
        }
    }
}

__global__ void k_upd0f(const float* __restrict__ dW0, const float* __restrict__ x,
                        const float* __restrict__ gb, float* __restrict__ out_dW0) {
    const int n4 = B * IN * HID / 4;
    const int stride = gridDim.x * blockDim.x;
    for (int i = blockIdx.x * blockDim.x + threadIdx.x; i < n4; i += stride) {
        const int j = n4 - 1 - i;                // reversed (ride L3 residency)
        const int h4 = j & (HID / 4 - 1);
        const int rest = j >> 7;
        const int q = rest & (IN - 1);
        const int b = rest >> 11;
        const float4 dw = ((const float4*)dW0)[j];
        const float xv = x[b * IN + q];
        const float4 g = *(const float4*)(gb + b * HID + h4 * 4);
        vf4 o;
        o.x = dw.x - LR * xv * g.x;
        o.y = dw.y - LR * xv * g.y;
        o.z = dw.z - LR * xv * g.z;
        o.w = dw.w - LR * xv * g.w;
        __builtin_nontemporal_store(o, (vf4*)out_dW0 + j);
    }
}

extern "C" void kernel_launch(void* const* d_in, const int* in_sizes, int n_in,
                              void* d_out, int out_size, void* d_ws, size_t ws_size,
                              hipStream_t stream) {
    (void)in_sizes; (void)n_in; (void)out_size; (void)ws_size;
    const float* x   = (const float*)d_in[0];
    const float* ut  = (const float*)d_in[1];
    const float* W0  = (const float*)d_in[2];
    const float* b0  = (const float*)d_in[3];
    const float* W1  = (const float*)d_in[4];
    const float* b1  = (const float*)d_in[5];
    const float* dW0 = (const float*)d_in[6];
    const float* db0 = (const float*)d_in[7];
    const float* dW1 = (const float*)d_in[8];
    const float* db1 = (const float*)d_in[9];

    float* ws  = (float*)d_ws;
    float* out = (float*)d_out;
    float* zp  = ws + WS_ZP;
    float* gbw = ws + WS_GBW;

    void* args[] = {(void*)&x, (void*)&ut, (void*)&W0, (void*)&b0, (void*)&W1,
                    (void*)&b1, (void*)&dW0, (void*)&db0, (void*)&dW1, (void*)&db1,
                    (void*)&out, (void*)&zp, (void*)&gbw};
    hipError_t err = hipLaunchCooperativeKernel((void*)k_mega, dim3(NBLK), dim3(NTHR),
                                                args, 0, stream);
    if (err != hipSuccess) {
        // deterministic fallback: proven 4-launch path
        (void)hipGetLastError();
        k_fwd1f<<<dim3(B, FQC), 128, 0, stream>>>(x, W0, dW0, ws + FWS_ZP);
        k_fwd2f<<<dim3(B, 8), 128, 0, stream>>>(ws + FWS_ZP, b0, db0, W1, dW1,
                                                ws + FWS_TANH, ws + FWS_ZOP);
        k_bwd1f<<<dim3(B, 8), 256, 0, stream>>>(ws + FWS_ZOP, b1, db1, ut, W1, dW1,
                                                ws + FWS_TANH, db0,
                                                out + O_L2N, out + O_DB1,
                                                out + O_DW1, out + O_DB0, ws + FWS_GB);
        k_upd0f<<<dim3(4096), 256, 0, stream>>>(dW0, x, ws + FWS_GB, out + O_DW0);
    }
}

// Round 9
// 161.636 us; speedup vs baseline: 3.4600x; 3.4600x over previous
//
#include <hip/hip_runtime.h>
#include <math.h>

#define LR 0.001f

// Sizes
#define B   64
#define IN  2048
#define HID 512
#define OUT 128
#define QC  16          // q-chunks for layer-1 partials
#define GB2 32          // batch-group size for the 2-group L3 pipeline

typedef float vf2 __attribute__((ext_vector_type(2)));
typedef float vf4 __attribute__((ext_vector_type(4)));

// ws layout (floats)
#define WS_ZP    0                       // [B][QC][HID] = 524288
#define WS_TANH  (WS_ZP + B*QC*HID)      // [B][HID]     = 32768
#define WS_ZOP   (WS_TANH + B*HID)       // [B][8][OUT]  = 65536
#define WS_GB    (WS_ZOP + B*8*OUT)      // [B][HID]     = 32768

// out layout (floats)
#define O_L2N   0
#define O_DW0   (B*OUT)
#define O_DB0   (O_DW0 + B*IN*HID)
#define O_DW1   (O_DB0 + B*HID)
#define O_DB1   (O_DW1 + B*HID*OUT)

// ---- layer-1 forward partials for one 32-b group:
// zp[b,qc,h] = sum_{q in chunk} x[b,q]*(W0[q,h]+dW0[b,q,h])
// grid (GB2, QC), block 128; thread owns 4 h (float4), block owns 128 q rows.
// Plain loads: we WANT this group's dW0 slab L3-resident for its upd0 launch.
__global__ void k_fwd1(const float* __restrict__ x, const float* __restrict__ W0,
                       const float* __restrict__ dW0, float* __restrict__ zp, int bb) {
    const int b = bb + blockIdx.x;
    const int q0 = blockIdx.y * (IN / QC);
    const int h = threadIdx.x * 4;        // 0..508
    const float* xr = x + b * IN;
    float4 acc = make_float4(0.f, 0.f, 0.f, 0.f);
    for (int qi = 0; qi < IN / QC; ++qi) {
        const int q = q0 + qi;
        const float xv = xr[q];
        const float4 w0 = *(const float4*)(W0 + q * HID + h);
        const float4 dw = *(const float4*)(dW0 + ((size_t)(b * IN + q)) * HID + h);
        acc.x += xv * (w0.x + dw.x);
        acc.y += xv * (w0.y + dw.y);
        acc.z += xv * (w0.z + dw.z);
        acc.w += xv * (w0.w + dw.w);
    }
    *(float4*)(zp + (b * QC + blockIdx.y) * HID + h) = acc;
}

// ---- layer-2 forward (+ fused bias/tanh), full batch:
// grid (B, 8), block 128; block owns 64 h rows, one o per thread.
__global__ void k_fwd2(const float* __restrict__ zp, const float* __restrict__ b0,
                       const float* __restrict__ db0, const float* __restrict__ W1,
                       const float* __restrict__ dW1, float* __restrict__ tanhv,
                       float* __restrict__ zop) {
    const int b = blockIdx.x;
    const int h0 = blockIdx.y * 64;
    const int tid = threadIdx.x;
    __shared__ float sth[64];
    if (tid < 64) {
        const int h = h0 + tid;
        float zsum = 0.f;
        const float* p = zp + (b * QC) * HID + h;
        #pragma unroll
        for (int qc = 0; qc < QC; ++qc) zsum += p[qc * HID];
        const float th = tanhf(zsum + b0[h] + db0[b * HID + h]);
        tanhv[b * HID + h] = th;
        sth[tid] = th;
    }
    __syncthreads();
    const int o = tid;
    float acc = 0.f;
    #pragma unroll 8
    for (int hi = 0; hi < 64; ++hi) {
        const int h = h0 + hi;
        acc += sth[hi] * (W1[h * OUT + o] + dW1[(b * HID + h) * OUT + o]);
    }
    zop[(b * 8 + blockIdx.y) * OUT + o] = acc;
}

// ---- fused middle + backward layer 2, full batch:
// grid (B, 8), block 256 (4 waves); wave owns 16 h rows; lane owns 2 o.
__global__ void k_bwd1(const float* __restrict__ zop, const float* __restrict__ b1,
                       const float* __restrict__ db1, const float* __restrict__ ut,
                       const float* __restrict__ W1, const float* __restrict__ dW1,
                       const float* __restrict__ tanhv, const float* __restrict__ db0,
                       float* __restrict__ out_l2n, float* __restrict__ out_db1,
                       float* __restrict__ out_dW1, float* __restrict__ out_db0,
                       float* __restrict__ gb) {
    const int b = blockIdx.x;
    const int w = threadIdx.x >> 6;
    const int lane = threadIdx.x & 63;
    const int o2 = lane * 2;

    float2 zo;
    zo.x = b1[o2]     + db1[b * OUT + o2];
    zo.y = b1[o2 + 1] + db1[b * OUT + o2 + 1];
    #pragma unroll
    for (int c = 0; c < 8; ++c) {
        const float2 zp2 = *(const float2*)(zop + (b * 8 + c) * OUT + o2);
        zo.x += zp2.x; zo.y += zp2.y;
    }
    const float2 tr = *(const float2*)(ut + b * OUT + o2);
    float a = zo.x * zo.x + zo.y * zo.y;
    float c2 = tr.x * tr.x + tr.y * tr.y;
    float d  = tr.x * zo.x + tr.y * zo.y;
    for (int off = 32; off; off >>= 1) {
        a  += __shfl_xor(a,  off, 64);
        c2 += __shfl_xor(c2, off, 64);
        d  += __shfl_xor(d,  off, 64);
    }
    const float l2 = a;                               // squared norm (as in source)
    const float nt = fmaxf(sqrtf(c2), 1e-12f);        // ||update_target||
    const float tdot = d / nt;                        // sum(t * out2)
    const float s = 2.0f * tdot / (l2 * l2);
    float2 g2;
    g2.x = -(tr.x / nt) / l2 + s * zo.x;
    g2.y = -(tr.y / nt) / l2 + s * zo.y;

    if (blockIdx.y == 0 && w == 0) {
        *(float2*)(out_l2n + b * OUT + o2) = make_float2(zo.x / l2, zo.y / l2);
        *(float2*)(out_db1 + b * OUT + o2) =
            make_float2(db1[b * OUT + o2] - LR * g2.x, db1[b * OUT + o2 + 1] - LR * g2.y);
    }

    for (int i = 0; i < 16; ++i) {
        const int h = blockIdx.y * 64 + w * 16 + i;
        const int idx = (b * HID + h) * OUT + o2;
        const float2 dw = *(const float2*)(dW1 + idx);
        const float2 w1 = *(const float2*)(W1 + h * OUT + o2);
        float part = g2.x * (w1.x + dw.x) + g2.y * (w1.y + dw.y);
        for (int off = 32; off; off >>= 1) part += __shfl_xor(part, off, 64);
        const float th = tanhv[b * HID + h];
        vf2 nd;
        nd.x = dw.x - LR * th * g2.x;
        nd.y = dw.y - LR * th * g2.y;
        __builtin_nontemporal_store(nd, (vf2*)(out_dW1 + idx));
        if (lane == 0) {
            const float gbv = (1.f - th * th) * part;
            gb[b * HID + h] = gbv;
            out_db0[b * HID + h] = db0[b * HID + h] - LR * gbv;
        }
    }
}

// ---- group update: new_d_weights_0 = dW0 - LR * x[b,q] * gb[b,h]
// Launched per 32-b group, ordered so this group's dW0 slab (134 MB) is the
// most-recently-read large block -> L3 hits. Plain loads (want the hits),
// NT stores (output stream never reused, must not evict the other slab).
__global__ void k_upd0(const float* __restrict__ dW0, const float* __restrict__ x,
                       const float* __restrict__ gb, float* __restrict__ out_dW0,
                       int bb) {
    const int n4 = GB2 * IN * HID / 4;   // 8,388,608 float4 per group
    const size_t base = (size_t)bb * IN * HID / 4;
    const int stride = gridDim.x * blockDim.x;
    for (int i = blockIdx.x * blockDim.x + threadIdx.x; i < n4; i += stride) {
        const size_t j = base + i;
        const int h4 = i & (HID / 4 - 1);        // 0..127
        const int rest = i >> 7;
        const int q = rest & (IN - 1);
        const int b = bb + (rest >> 11);
        const float4 dw = ((const float4*)dW0)[j];
        const float xv = x[b * IN + q];
        const float4 g = *(const float4*)(gb + b * HID + h4 * 4);
        vf4 o;
        o.x = dw.x - LR * xv * g.x;
        o.y = dw.y - LR * xv * g.y;
        o.z = dw.z - LR * xv * g.z;
        o.w = dw.w - LR * xv * g.w;
        __builtin_nontemporal_store(o, (vf4*)out_dW0 + j);
    }
}

extern "C" void kernel_launch(void* const* d_in, const int* in_sizes, int n_in,
                              void* d_out, int out_size, void* d_ws, size_t ws_size,
                              hipStream_t stream) {
    (void)in_sizes; (void)n_in; (void)out_size; (void)ws_size;
    const float* x   = (const float*)d_in[0];
    const float* ut  = (const float*)d_in[1];
    const float* W0  = (const float*)d_in[2];
    const float* b0  = (const float*)d_in[3];
    const float* W1  = (const float*)d_in[4];
    const float* b1  = (const float*)d_in[5];
    const float* dW0 = (const float*)d_in[6];
    const float* db0 = (const float*)d_in[7];
    const float* dW1 = (const float*)d_in[8];
    const float* db1 = (const float*)d_in[9];

    float* ws  = (float*)d_ws;
    float* out = (float*)d_out;

    // Group order: read G1 first, G0 second => G0 is MRU when upd0(G0) runs;
    // G1's remnant serves upd0(G1).
    k_fwd1<<<dim3(GB2, QC), 128, 0, stream>>>(x, W0, dW0, ws + WS_ZP, GB2);  // G1
    k_fwd1<<<dim3(GB2, QC), 128, 0, stream>>>(x, W0, dW0, ws + WS_ZP, 0);    // G0
    k_fwd2<<<dim3(B, 8), 128, 0, stream>>>(ws + WS_ZP, b0, db0, W1, dW1,
                                           ws + WS_TANH, ws + WS_ZOP);
    k_bwd1<<<dim3(B, 8), 256, 0, stream>>>(ws + WS_ZOP, b1, db1, ut, W1, dW1,
                                           ws + WS_TANH, db0,
                                           out + O_L2N, out + O_DB1,
                                           out + O_DW1, out + O_DB0, ws + WS_GB);
    k_upd0<<<dim3(4096), 256, 0, stream>>>(dW0, x, ws + WS_GB, out + O_DW0, 0);    // G0
    k_upd0<<<dim3(4096), 256, 0, stream>>>(dW0, x, ws + WS_GB, out + O_DW0, GB2);  // G1
}